// Round 1
// baseline (393.376 us; speedup 1.0000x reference)
//
#include <hip/hip_runtime.h>
#include <hip/hip_bf16.h>

#define IN_FEAT 37
#define IN_CH 512
#define NUM_HEADS 8
#define DEPTH 64
#define BB 4
#define SS 2048
#define NROWS (BB * SS)

typedef unsigned short u16;
typedef __attribute__((ext_vector_type(8))) short bf16x8;
typedef __attribute__((ext_vector_type(4))) float f32x4;

#define MFMA16(a, b, c) __builtin_amdgcn_mfma_f32_16x16x32_bf16(a, b, c, 0, 0, 0)

__device__ __forceinline__ u16 f2bf(float f) {
    union { float f; unsigned u; } v;
    v.f = f;
    unsigned r = v.u + 0x7fffu + ((v.u >> 16) & 1u);
    return (u16)(r >> 16);
}

// ---------------------------------------------------------------------------
// Kernel 1: fused QKV projection.
// x [B*S, 37] fp32 -> q,k bf16 [B,H,S,D], v bf16 transposed [B,H,D,S].
// One block = 64 rows. Q/K part: lane = d (coalesced W reads + writes, x row
// broadcast from LDS). V part: lane = s (coalesced transposed writes).
// ---------------------------------------------------------------------------
__global__ __launch_bounds__(256) void qkv_proj(
    const float* __restrict__ x,
    const float* __restrict__ Wq, const float* __restrict__ bq,
    const float* __restrict__ Wk, const float* __restrict__ bk,
    const float* __restrict__ Wv, const float* __restrict__ bv,
    u16* __restrict__ qo, u16* __restrict__ ko, u16* __restrict__ vo)
{
    __shared__ float xl[64][39];  // pad 37->39: V-part LDS reads 2-way (free)
    const int t = threadIdx.x;
    const int row0 = blockIdx.x * 64;

    for (int idx = t; idx < 64 * IN_FEAT; idx += 256) {
        int r = idx / IN_FEAT, i = idx - r * IN_FEAT;
        xl[r][i] = x[row0 * IN_FEAT + idx];
    }
    __syncthreads();

    // ---- Q and K ----
    {
        const int d = t & 63, sl = t >> 6;
        for (int h = 0; h < NUM_HEADS; ++h) {
            const int c = h * 64 + d;
            float wq[IN_FEAT], wk[IN_FEAT];
#pragma unroll
            for (int i = 0; i < IN_FEAT; ++i) {
                wq[i] = Wq[i * IN_CH + c];
                wk[i] = Wk[i * IN_CH + c];
            }
            const float bqv = bq[c], bkv = bk[c];
            for (int so = 0; so < 64; so += 4) {
                const int s = so + sl;
                float aq = bqv, ak = bkv;
#pragma unroll
                for (int i = 0; i < IN_FEAT; ++i) {
                    float xv = xl[s][i];
                    aq += xv * wq[i];
                    ak += xv * wk[i];
                }
                const int row = row0 + s;
                const int b = row >> 11, ss = row & 2047;
                const int base = ((b * NUM_HEADS + h) * SS + ss) * DEPTH + d;
                qo[base] = f2bf(aq);
                ko[base] = f2bf(ak);
            }
        }
    }
    // ---- V (transposed store) ----
    {
        const int s = t & 63, dl = t >> 6;
        const int row = row0 + s;
        const int b = row >> 11, ss = row & 2047;
        for (int h = 0; h < NUM_HEADS; ++h) {
            for (int dof = 0; dof < 64; dof += 4) {
                const int d = dof + dl;
                const int c = h * 64 + d;
                float av = bv[c];
#pragma unroll
                for (int i = 0; i < IN_FEAT; ++i) av += xl[s][i] * Wv[i * IN_CH + c];
                vo[((b * NUM_HEADS + h) * DEPTH + d) * SS + ss] = f2bf(av);
            }
        }
    }
}

// ---------------------------------------------------------------------------
// Kernel 2: Wd fp32 [512,512] -> WdT bf16 [512,512] (transposed)
// ---------------------------------------------------------------------------
__global__ __launch_bounds__(256) void wd_trans(
    const float* __restrict__ Wd, u16* __restrict__ WdT)
{
    int idx = blockIdx.x * 256 + threadIdx.x;
    int r = idx >> 9, c = idx & 511;
    WdT[c * IN_CH + r] = f2bf(Wd[idx]);
}

// ---------------------------------------------------------------------------
// Kernel 3: flash attention. grid (S/64, B*H), block 256 = 4 waves.
// Wave w owns 16 q-rows. 32-key KV steps: 4 QK MFMAs -> log2-domain online
// softmax -> P via swizzled wave-private LDS -> 4 PV MFMAs.
// q,k: [B,H,S,D]; v: [B,H,D,S]; out: bf16 [B,S,512]
// ---------------------------------------------------------------------------
__global__ __launch_bounds__(256) void attn_kernel(
    const u16* __restrict__ qg, const u16* __restrict__ kg,
    const u16* __restrict__ vg, u16* __restrict__ og)
{
    __shared__ u16 Plds[4 * 16 * 32];
    const int tid = threadIdx.x;
    const int w = tid >> 6, lane = tid & 63;
    const int g = lane >> 4, l15 = lane & 15;
    const int bh = blockIdx.y;
    const int q0 = blockIdx.x * 64 + w * 16;
    const float SC = 0.125f * 1.44269504f;  // scale * log2(e)

    bf16x8 qA0 = *(const bf16x8*)&qg[(bh * SS + q0 + l15) * DEPTH + g * 8];
    bf16x8 qA1 = *(const bf16x8*)&qg[(bh * SS + q0 + l15) * DEPTH + 32 + g * 8];

    f32x4 O[4];
    float mreg[4], lreg[4];
#pragma unroll
    for (int nt = 0; nt < 4; ++nt) O[nt] = (f32x4){0.f, 0.f, 0.f, 0.f};
#pragma unroll
    for (int r = 0; r < 4; ++r) { mreg[r] = -__builtin_inff(); lreg[r] = 0.f; }

    // LDS read offset (A-fragment of P): row=l15, cols g*8..g*8+7, XOR-swizzled
    const int roff = w * 512 + l15 * 32 + ((g ^ ((l15 >> 1) & 3)) << 3);

    for (int kv0 = 0; kv0 < SS; kv0 += 32) {
        const u16* kbase = &kg[(bh * SS + kv0) * DEPTH];
        bf16x8 k00 = *(const bf16x8*)&kbase[l15 * DEPTH + g * 8];
        bf16x8 k01 = *(const bf16x8*)&kbase[l15 * DEPTH + 32 + g * 8];
        bf16x8 k10 = *(const bf16x8*)&kbase[(16 + l15) * DEPTH + g * 8];
        bf16x8 k11 = *(const bf16x8*)&kbase[(16 + l15) * DEPTH + 32 + g * 8];

        f32x4 s0 = (f32x4){0.f, 0.f, 0.f, 0.f};
        f32x4 s1 = (f32x4){0.f, 0.f, 0.f, 0.f};
        s0 = MFMA16(qA0, k00, s0);
        s0 = MFMA16(qA1, k01, s0);
        s1 = MFMA16(qA0, k10, s1);
        s1 = MFMA16(qA1, k11, s1);

        // online softmax (log2 domain); row r of this wave-tile = g*4 + reg
        float p0[4], p1[4], mx[4], sum[4], al[4];
#pragma unroll
        for (int r = 0; r < 4; ++r) {
            p0[r] = s0[r] * SC;
            p1[r] = s1[r] * SC;
            mx[r] = fmaxf(p0[r], p1[r]);
        }
#pragma unroll
        for (int msk = 1; msk <= 8; msk <<= 1)
#pragma unroll
            for (int r = 0; r < 4; ++r) mx[r] = fmaxf(mx[r], __shfl_xor(mx[r], msk, 64));
#pragma unroll
        for (int r = 0; r < 4; ++r) {
            float mn = fmaxf(mreg[r], mx[r]);
            al[r] = exp2f(mreg[r] - mn);
            mreg[r] = mn;
            p0[r] = exp2f(p0[r] - mn);
            p1[r] = exp2f(p1[r] - mn);
            sum[r] = p0[r] + p1[r];
        }
#pragma unroll
        for (int msk = 1; msk <= 8; msk <<= 1)
#pragma unroll
            for (int r = 0; r < 4; ++r) sum[r] += __shfl_xor(sum[r], msk, 64);
#pragma unroll
        for (int r = 0; r < 4; ++r) lreg[r] = lreg[r] * al[r] + sum[r];
#pragma unroll
        for (int nt = 0; nt < 4; ++nt)
#pragma unroll
            for (int r = 0; r < 4; ++r) O[nt][r] *= al[r];

        // P (C-layout) -> LDS (XOR-swizzled) -> A-fragment
#pragma unroll
        for (int r = 0; r < 4; ++r) {
            const int row = g * 4 + r;
            const int xorv = ((row >> 1) & 3) << 3;
            Plds[w * 512 + row * 32 + ((0 * 16 + l15) ^ xorv)] = f2bf(p0[r]);
            Plds[w * 512 + row * 32 + ((1 * 16 + l15) ^ xorv)] = f2bf(p1[r]);
        }
        bf16x8 pA = *(const bf16x8*)&Plds[roff];

#pragma unroll
        for (int nt = 0; nt < 4; ++nt) {
            bf16x8 bV = *(const bf16x8*)&vg[(bh * DEPTH + nt * 16 + l15) * SS + kv0 + g * 8];
            O[nt] = MFMA16(pA, bV, O[nt]);
        }
    }

    // epilogue
    const int b = bh >> 3, h = bh & 7;
    float inv[4];
#pragma unroll
    for (int r = 0; r < 4; ++r) inv[r] = 1.0f / lreg[r];
#pragma unroll
    for (int nt = 0; nt < 4; ++nt)
#pragma unroll
        for (int r = 0; r < 4; ++r) {
            const int s = q0 + g * 4 + r;
            const int col = h * 64 + nt * 16 + l15;
            og[(b * SS + s) * IN_CH + col] = f2bf(O[nt][r] * inv[r]);
        }
}

// ---------------------------------------------------------------------------
// Kernel 4: output GEMM. A = attn bf16 [8192,512], BT = WdT bf16 [512,512],
// out fp32 [8192,512] = A @ Wd + bd. Block 256 = 4 waves, tile 64x64.
// ---------------------------------------------------------------------------
__global__ __launch_bounds__(256) void out_gemm(
    const u16* __restrict__ A, const u16* __restrict__ BT,
    const float* __restrict__ bd, float* __restrict__ out)
{
    const int tid = threadIdx.x;
    const int w = tid >> 6, lane = tid & 63;
    const int g = lane >> 4, l15 = lane & 15;
    const int m0 = blockIdx.x * 64 + w * 16;
    const int n0 = blockIdx.y * 64;

    f32x4 acc[4];
#pragma unroll
    for (int nt = 0; nt < 4; ++nt) acc[nt] = (f32x4){0.f, 0.f, 0.f, 0.f};

    for (int k0 = 0; k0 < IN_CH; k0 += 32) {
        bf16x8 a = *(const bf16x8*)&A[(m0 + l15) * IN_CH + k0 + g * 8];
#pragma unroll
        for (int nt = 0; nt < 4; ++nt) {
            bf16x8 b = *(const bf16x8*)&BT[(n0 + nt * 16 + l15) * IN_CH + k0 + g * 8];
            acc[nt] = MFMA16(a, b, acc[nt]);
        }
    }
#pragma unroll
    for (int nt = 0; nt < 4; ++nt)
#pragma unroll
        for (int r = 0; r < 4; ++r) {
            const int m = m0 + g * 4 + r;
            const int n = n0 + nt * 16 + l15;
            out[m * IN_CH + n] = acc[nt][r] + bd[n];
        }
}

// ---------------------------------------------------------------------------
extern "C" void kernel_launch(void* const* d_in, const int* in_sizes, int n_in,
                              void* d_out, int out_size, void* d_ws, size_t ws_size,
                              hipStream_t stream)
{
    const float* x  = (const float*)d_in[0];
    const float* Wq = (const float*)d_in[1];
    const float* bq = (const float*)d_in[2];
    const float* Wk = (const float*)d_in[3];
    const float* bk = (const float*)d_in[4];
    const float* Wv = (const float*)d_in[5];
    const float* bv = (const float*)d_in[6];
    const float* Wd = (const float*)d_in[7];
    const float* bd = (const float*)d_in[8];
    float* out = (float*)d_out;

    u16* ws  = (u16*)d_ws;
    u16* q   = ws;                       // 8192*512 bf16
    u16* k   = q + NROWS * IN_CH;        // 8192*512
    u16* vT  = k + NROWS * IN_CH;        // 8192*512 (as [B,H,D,S])
    u16* ao  = vT + NROWS * IN_CH;       // 8192*512
    u16* WdT = ao + NROWS * IN_CH;       // 512*512

    qkv_proj<<<dim3(NROWS / 64), dim3(256), 0, stream>>>(x, Wq, bq, Wk, bk, Wv, bv, q, k, vT);
    wd_trans<<<dim3(IN_CH * IN_CH / 256), dim3(256), 0, stream>>>(Wd, WdT);
    attn_kernel<<<dim3(SS / 64, BB * NUM_HEADS), dim3(256), 0, stream>>>(q, k, vT, ao);
    out_gemm<<<dim3(NROWS / 64, IN_CH / 64), dim3(256), 0, stream>>>(ao, WdT, bd, out);
}